// Round 9
// baseline (119.620 us; speedup 1.0000x reference)
//
#include <hip/hip_runtime.h>

#define BB 8
#define CC 64
#define HH 96
#define WW 96
#define OO 64
#define KK 3
#define K2 9
#define HW (HH*WW)      // 9216
#define NOFF 18
#define NPIX (BB*HW)    // 73728
#define MT 64           // pixels per dcn block
#define NTILE (HW/MT)   // 144 tiles per image

typedef _Float16 f16;
typedef __attribute__((ext_vector_type(2))) _Float16 f16x2;
typedef __attribute__((ext_vector_type(4))) _Float16 f16x4;
typedef __attribute__((ext_vector_type(4))) float f32x4;
typedef __attribute__((ext_vector_type(4))) unsigned int uint4v;

// Legacy CDNA spelling (v_mfma_f32_16x16x16_f16): no __has_builtin guard —
// that macro is false on the HOST pass of HIP's dual compile (R8 lesson).
#define MFMA16(a,b,c) __builtin_amdgcn_mfma_f32_16x16x16f16(a,b,c,0,0,0)

#if __has_builtin(__builtin_amdgcn_fdot2)
__device__ __forceinline__ float dot2u(unsigned a, unsigned b, float c) {
  return __builtin_amdgcn_fdot2(__builtin_bit_cast(f16x2, a),
                                __builtin_bit_cast(f16x2, b), c, false);
}
#else
__device__ __forceinline__ float dot2u(unsigned a, unsigned b, float c) {
  f16x2 ha = __builtin_bit_cast(f16x2, a), hb = __builtin_bit_cast(f16x2, b);
  return c + (float)ha[0] * (float)hb[0] + (float)ha[1] * (float)hb[1];
}
#endif

__device__ __forceinline__ f16x2 bch(unsigned u) { return __builtin_bit_cast(f16x2, u); }
__device__ __forceinline__ unsigned bcu(f16x2 h) { return __builtin_bit_cast(unsigned, h); }

// LDS slot swizzle (row stride 128 B = 8 slots of 16 B) — verified R4/R5
__device__ __forceinline__ int swz(int row, int g) {
  return g ^ (((row >> 2) ^ ((row & 3) << 1)) & 7);
}

// ---------------- Kernel T: NCHW fp32 -> NHWC f16 (verified R5) -------------
__global__ __launch_bounds__(256) void transpose_kernel(
    const float* __restrict__ x, unsigned short* __restrict__ xt) {
  int t = threadIdx.x;
  int px = blockIdx.x * 64 + (t & 63);
  int cg = t >> 6;
  int b = px / HW, hw = px % HW;
  const float* xp = x + (size_t)b * CC * HW + (size_t)(cg * 16) * HW + hw;
  f16 r[16];
  #pragma unroll
  for (int i = 0; i < 16; ++i) r[i] = (f16)xp[i * HW];
  uint4v v0, v1;
  #pragma unroll
  for (int q = 0; q < 4; ++q) {
    f16x2 a = {r[q*2], r[q*2+1]};       v0[q] = bcu(a);
    f16x2 bq = {r[8+q*2], r[8+q*2+1]};  v1[q] = bcu(bq);
  }
  uint4v* dst = (uint4v*)(xt + (size_t)px * CC + cg * 16);
  dst[0] = v0; dst[1] = v1;
}

// ---------------- Kernel W: w_dcn [O][C][K2] fp32 -> wt [K2][O][C] f16 ------
__global__ void wprep_kernel(const float* __restrict__ w_dcn,
                             unsigned short* __restrict__ wt) {
  int idx = blockIdx.x * 256 + threadIdx.x;
  int k = idx / (OO * CC);
  int o = (idx / CC) % OO;
  int c = idx % CC;
  f16 h = (f16)w_dcn[(o * CC + c) * K2 + k];
  wt[idx] = __builtin_bit_cast(unsigned short, h);
}

// ---------------- Kernel O: offset conv via dot2 (verified R5) --------------
#define JW 72
#define DOT4(xv, wv, a) do { a = dot2u((xv)[0],(wv)[0],a); a = dot2u((xv)[1],(wv)[1],a); \
                             a = dot2u((xv)[2],(wv)[2],a); a = dot2u((xv)[3],(wv)[3],a); } while(0)
#define DECLSET(R) uint4v R##0,R##1,R##2,R##3,R##4,R##5,R##6,R##7; bool vld##R = false;
#define LOADT(kt_, R) do { int ky=(kt_)/3, kx=(kt_)%3; int y=h-1+ky, xx=w-1+kx; \
  vld##R = ((unsigned)y<HH)&&((unsigned)xx<WW); \
  int yc=min(max(y,0),HH-1), xc=min(max(xx,0),WW-1); \
  const uint4v* xr_ = xtb + (size_t)(yc*WW+xc)*8; \
  R##0=xr_[0];R##1=xr_[1];R##2=xr_[2];R##3=xr_[3];R##4=xr_[4];R##5=xr_[5];R##6=xr_[6];R##7=xr_[7]; } while(0)
#define USET(kt_, R) do { if (vld##R) { \
  _Pragma("unroll") \
  for (int ji = 0; ji < 5; ++ji) { int j = jg + ji*4; \
    const uint4v* wr_ = (const uint4v*)&wl[((kt_)*NOFF + j)*JW]; \
    float a = acc[ji]; \
    DOT4(R##0,wr_[0],a); DOT4(R##1,wr_[1],a); DOT4(R##2,wr_[2],a); DOT4(R##3,wr_[3],a); \
    DOT4(R##4,wr_[4],a); DOT4(R##5,wr_[5],a); DOT4(R##6,wr_[6],a); DOT4(R##7,wr_[7],a); \
    if (j < NOFF) acc[ji] = a; } } } while(0)

__global__ __launch_bounds__(256) void offconv_kernel(
    const unsigned short* __restrict__ xt, const float* __restrict__ w_off,
    const float* __restrict__ b_off, float* __restrict__ offset) {
  __shared__ unsigned short wl[K2 * NOFF * JW + 2 * JW];
  int t = threadIdx.x;
  for (int i = t; i < K2 * NOFF * CC; i += 256) {
    int kt = i / (NOFF * CC);
    int r = i - kt * (NOFF * CC);
    int j = r >> 6, c = r & 63;
    f16 h = (f16)w_off[(j * CC + c) * K2 + kt];
    wl[(kt * NOFF + j) * JW + c] = __builtin_bit_cast(unsigned short, h);
  }
  __syncthreads();

  int px = blockIdx.x * 64 + (t >> 2);
  int jg = t & 3;
  int b = px / HW, hw = px % HW;
  int h = hw / WW, w = hw % WW;

  float acc[5];
  #pragma unroll
  for (int ji = 0; ji < 5; ++ji) {
    int j = jg + ji * 4;
    acc[ji] = (j < NOFF) ? b_off[j] : 0.f;
  }

  const uint4v* xtb = (const uint4v*)(xt + (size_t)b * HW * CC);
  DECLSET(A); DECLSET(B);
  LOADT(0, A);
  LOADT(1, B);
  #pragma unroll
  for (int kt = 0; kt < 7; kt += 2) {
    USET(kt, A);     LOADT(kt + 2, A);
    USET(kt + 1, B); if (kt + 3 < K2) LOADT(kt + 3, B);
  }
  USET(8, A);

  float* op = offset + (size_t)b * NOFF * HW + hw;
  #pragma unroll
  for (int ji = 0; ji < 5; ++ji) {
    int j = jg + ji * 4;
    if (j < NOFF) op[j * HW] = acc[ji];
  }
}

// ---------------- shared phase-0 macro (verified R3..R5) --------------------
#define PHASE0_BILINEAR \
  for (int p = t; p < 576; p += 256) { \
    int k = p >> 6, m = p & 63; \
    int hw = hw0 + m; \
    int h = hw / WW, w = hw % WW; \
    int ky = k / KK, kx = k % KK; \
    float py = offb[(2 * k) * HW + m]     + (float)(h - 1 + ky); \
    float px = offb[(2 * k + 1) * HW + m] + (float)(w - 1 + kx); \
    float y0f = floorf(py), x0f = floorf(px); \
    float wy = py - y0f, wx = px - x0f; \
    int y0 = (int)y0f, x0 = (int)x0f; \
    int y1 = y0 + 1, x1 = x0 + 1; \
    bool vy0 = (unsigned)y0 < HH, vy1 = (unsigned)y1 < HH; \
    bool vx0 = (unsigned)x0 < WW, vx1 = (unsigned)x1 < WW; \
    int cy0 = min(max(y0, 0), HH - 1), cy1 = min(max(y1, 0), HH - 1); \
    int cx0 = min(max(x0, 0), WW - 1), cx1 = min(max(x1, 0), WW - 1); \
    pwt[p * 4 + 0] = (1.f - wy) * (1.f - wx) * ((vy0 && vx0) ? 1.f : 0.f); \
    pwt[p * 4 + 1] = (1.f - wy) * wx         * ((vy0 && vx1) ? 1.f : 0.f); \
    pwt[p * 4 + 2] = wy * (1.f - wx)         * ((vy1 && vx0) ? 1.f : 0.f); \
    pwt[p * 4 + 3] = wy * wx                 * ((vy1 && vx1) ? 1.f : 0.f); \
    pidx[p * 4 + 0] = (unsigned short)(cy0 * WW + cx0); \
    pidx[p * 4 + 1] = (unsigned short)(cy0 * WW + cx1); \
    pidx[p * 4 + 2] = (unsigned short)(cy1 * WW + cx0); \
    pidx[p * 4 + 3] = (unsigned short)(cy1 * WW + cx1); \
  }

#define STAGE_BODY \
  *(uint4v*)&Bl[sm * 128 + (((cb * 2 + 0) ^ fs) << 4)] = wv0; \
  *(uint4v*)&Bl[sm * 128 + (((cb * 2 + 1) ^ fs) << 4)] = wv1; \
  { \
    f16 h0 = (f16)wq[0], h1 = (f16)wq[1], h2 = (f16)wq[2], h3 = (f16)wq[3]; \
    f16x2 p0 = {h0, h0}, p1 = {h1, h1}, p2 = {h2, h2}, p3 = {h3, h3}; \
    uint4v pa, pb2; \
    _Pragma("unroll") \
    for (int q = 0; q < 4; ++q) { \
      f16x2 s  = p0 * bch(c0a[q]) + p1 * bch(c1a[q]) \
               + p2 * bch(c2a[q]) + p3 * bch(c3a[q]); \
      pa[q] = bcu(s); \
      f16x2 s2 = p0 * bch(c0b[q]) + p1 * bch(c1b[q]) \
               + p2 * bch(c2b[q]) + p3 * bch(c3b[q]); \
      pb2[q] = bcu(s2); \
    } \
    *(uint4v*)&Al[sm * 128 + (((cb * 2 + 0) ^ fs) << 4)] = pa; \
    *(uint4v*)&Al[sm * 128 + (((cb * 2 + 1) ^ fs) << 4)] = pb2; \
  }

#define ISSUE_LAMBDA \
  auto ISSUE = [&](int k) { \
    int pb = (k * 64 + sm) * 4; \
    int i0 = ((int)pidx[pb + 0]) << 7; \
    int i1 = ((int)pidx[pb + 1]) << 7; \
    int i2 = ((int)pidx[pb + 2]) << 7; \
    int i3 = ((int)pidx[pb + 3]) << 7; \
    wq = *(const f32x4*)&pwt[pb]; \
    int co = cb * 32; \
    c0a = *(const uint4v*)(xb + i0 + co); c0b = *(const uint4v*)(xb + i0 + co + 16); \
    c1a = *(const uint4v*)(xb + i1 + co); c1b = *(const uint4v*)(xb + i1 + co + 16); \
    c2a = *(const uint4v*)(xb + i2 + co); c2b = *(const uint4v*)(xb + i2 + co + 16); \
    c3a = *(const uint4v*)(xb + i3 + co); c3b = *(const uint4v*)(xb + i3 + co + 16); \
    const uint4v* wk = (const uint4v*)((const char*)wt \
                        + ((size_t)k * OO + sm) * (CC * 2) + cb * 32); \
    wv0 = wk[0]; wv1 = wk[1]; \
  };

// ---------------- Kernel D1: dcn via v_mfma_f32_16x16x16_f16 ----------------
// Classic gfx942-documented layout: A row=l&15, k=4*(l>>4)+e (e=0..3);
// B n=l&15, same k; C/D col=l&15, row=(l>>4)*4+reg. Per tap: 4 k-chunks of 16.
__global__ __launch_bounds__(256) void dcn_mfma16(
    const unsigned short* __restrict__ xt,
    const float* __restrict__ offset,
    const unsigned short* __restrict__ wt,
    float* __restrict__ out) {
  __shared__ unsigned short pidx[576 * 4];
  __shared__ __align__(16) float pwt[576 * 4];
  __shared__ char Al[64 * 128];
  __shared__ char Bl[64 * 128];

  int t = threadIdx.x;
  int blk = blockIdx.x;
  int b = blk / NTILE;
  int hw0 = (blk % NTILE) * MT;

  const char*  xb   = (const char*)(xt + (size_t)b * HW * CC);
  const float* offb = offset + (size_t)b * NOFF * HW + hw0;

  PHASE0_BILINEAR
  __syncthreads();

  int sm = (t & 15) + (t >> 6) * 16;
  int cb = (t >> 4) & 3;
  int fs = ((sm >> 2) ^ ((sm & 3) << 1)) & 7;

  // wave geometry
  int wv = t >> 6;
  int l  = t & 63;
  int lr = l & 15, lh = l >> 4;

  // tap-invariant fragment byte offsets: chunk q covers channels q*16..+15;
  // lane covers channels q*16 + 4*lh + e  ->  slot 2q+(lh>>1), byte (lh&1)*8
  int Ra = wv * 16 + lr;
  int aoff[4];
  int boff[4][4];
  #pragma unroll
  for (int q = 0; q < 4; ++q) {
    aoff[q] = Ra * 128 + (swz(Ra, 2 * q + (lh >> 1)) << 4) + ((lh & 1) << 3);
    #pragma unroll
    for (int nb = 0; nb < 4; ++nb) {
      int Rb = nb * 16 + lr;
      boff[nb][q] = Rb * 128 + (swz(Rb, 2 * q + (lh >> 1)) << 4) + ((lh & 1) << 3);
    }
  }

  f32x4 acc[4];
  #pragma unroll
  for (int nb = 0; nb < 4; ++nb) acc[nb] = (f32x4){0.f, 0.f, 0.f, 0.f};

  uint4v c0a, c0b, c1a, c1b, c2a, c2b, c3a, c3b, wv0, wv1;
  f32x4 wq;
  ISSUE_LAMBDA

  ISSUE(0);
  for (int k = 0; k < K2; ++k) {
    STAGE_BODY
    __syncthreads();
    if (k < K2 - 1) ISSUE(k + 1);

    #pragma unroll
    for (int q = 0; q < 4; ++q) {
      f16x4 aq = *(const f16x4*)&Al[aoff[q]];
      #pragma unroll
      for (int nb = 0; nb < 4; ++nb) {
        f16x4 bq = *(const f16x4*)&Bl[boff[nb][q]];
        acc[nb] = MFMA16(aq, bq, acc[nb]);
      }
    }
    __syncthreads();
  }

  float* ob = out + (size_t)b * OO * HW;
  #pragma unroll
  for (int nb = 0; nb < 4; ++nb) {
    int o = nb * 16 + lr;
    int m = wv * 16 + lh * 4;
    *(f32x4*)(ob + (size_t)o * HW + hw0 + m) = acc[nb];
  }
}

// ---------------- Kernel C: checker (8 samples, f32 reference) --------------
__global__ __launch_bounds__(256) void check_kernel(
    const float* __restrict__ x, const float* __restrict__ offset,
    const float* __restrict__ w_dcn, const float* __restrict__ out,
    int* __restrict__ flag) {
  // samples hit all wv/nb/lh/reg/lr cells and several blocks/batches
  const int sb[8]  = {0, 0, 0, 0, 2, 4, 6, 7};
  const int so[8]  = {0, 17, 34, 55, 9, 28, 45, 63};
  const int shw[8] = {0, 21, 42, 63, 1000, 5000, 9000, 9215};
  __shared__ int ok[8];
  int t = threadIdx.x;
  int s = t >> 5, j = t & 31;
  int b = sb[s], o = so[s], hw = shw[s];
  int h = hw / WW, w = hw % WW;
  const float* offp = offset + (size_t)b * NOFF * HW + hw;
  const float* xbp  = x + (size_t)b * CC * HW;

  float part = 0.f;
  for (int i = 0; i < 18; ++i) {
    int tau = j + 32 * i;
    int k = tau >> 6, c = tau & 63;
    int ky = k / KK, kx = k % KK;
    float py = offp[(2 * k) * HW]     + (float)(h - 1 + ky);
    float px = offp[(2 * k + 1) * HW] + (float)(w - 1 + kx);
    float y0f = floorf(py), x0f = floorf(px);
    float wy = py - y0f, wx = px - x0f;
    int y0 = (int)y0f, x0 = (int)x0f;
    int y1 = y0 + 1, x1 = x0 + 1;
    bool vy0 = (unsigned)y0 < HH, vy1 = (unsigned)y1 < HH;
    bool vx0 = (unsigned)x0 < WW, vx1 = (unsigned)x1 < WW;
    int cy0 = min(max(y0, 0), HH - 1), cy1 = min(max(y1, 0), HH - 1);
    int cx0 = min(max(x0, 0), WW - 1), cx1 = min(max(x1, 0), WW - 1);
    const float* xc = xbp + (size_t)c * HW;
    float v = (1.f - wy) * (1.f - wx) * ((vy0 && vx0) ? xc[cy0 * WW + cx0] : 0.f)
            + (1.f - wy) * wx         * ((vy0 && vx1) ? xc[cy0 * WW + cx1] : 0.f)
            + wy * (1.f - wx)         * ((vy1 && vx0) ? xc[cy1 * WW + cx0] : 0.f)
            + wy * wx                 * ((vy1 && vx1) ? xc[cy1 * WW + cx1] : 0.f);
    part = fmaf(v, w_dcn[(o * CC + c) * K2 + k], part);
  }
  #pragma unroll
  for (int d = 16; d > 0; d >>= 1) part += __shfl_down(part, d, 32);
  if (j == 0) {
    float got = out[(size_t)b * OO * HW + (size_t)o * HW + hw];
    ok[s] = (fabsf(part - got) <= 0.05f) ? 1 : 0;
  }
  __syncthreads();
  if (t == 0) {
    int all = 1;
    #pragma unroll
    for (int i = 0; i < 8; ++i) all &= ok[i];
    flag[0] = all;
  }
}

// ---------------- Kernel D2: dot2 fallback (verified R5), flag-gated --------
__global__ __launch_bounds__(256) void dcn_fb(
    const unsigned short* __restrict__ xt,
    const float* __restrict__ offset,
    const unsigned short* __restrict__ wt,
    float* __restrict__ out, const int* __restrict__ flag) {
  if (flag[0] != 0) return;   // MFMA path verified good -> nothing to do

  __shared__ unsigned short pidx[576 * 4];
  __shared__ __align__(16) float pwt[576 * 4];
  __shared__ char Al[64 * 128];
  __shared__ char Bl[64 * 128];

  int t = threadIdx.x;
  int blk = blockIdx.x;
  int b = blk / NTILE;
  int hw0 = (blk % NTILE) * MT;

  const char*  xb   = (const char*)(xt + (size_t)b * HW * CC);
  const float* offb = offset + (size_t)b * NOFF * HW + hw0;

  PHASE0_BILINEAR
  __syncthreads();

  int sm = (t & 15) + (t >> 6) * 16;
  int cb = (t >> 4) & 3;
  int fs = ((sm >> 2) ^ ((sm & 3) << 1)) & 7;
  int mg = t >> 4;
  int og = t & 15;

  float acc[4][4];
  #pragma unroll
  for (int p = 0; p < 4; ++p)
    #pragma unroll
    for (int q = 0; q < 4; ++q) acc[p][q] = 0.f;

  uint4v c0a, c0b, c1a, c1b, c2a, c2b, c3a, c3b, wv0, wv1;
  f32x4 wq;
  ISSUE_LAMBDA

  ISSUE(0);
  for (int k = 0; k < K2; ++k) {
    STAGE_BODY
    __syncthreads();
    if (k < K2 - 1) ISSUE(k + 1);

    #pragma unroll
    for (int g = 0; g < 8; ++g) {
      uint4v av[4], bv[4];
      #pragma unroll
      for (int p = 0; p < 4; ++p) {
        int row = mg * 4 + p;
        av[p] = *(const uint4v*)&Al[row * 128 + (swz(row, g) << 4)];
      }
      #pragma unroll
      for (int q = 0; q < 4; ++q) {
        int row = og * 4 + q;
        bv[q] = *(const uint4v*)&Bl[row * 128 + (swz(row, g) << 4)];
      }
      #pragma unroll
      for (int p = 0; p < 4; ++p)
        #pragma unroll
        for (int q = 0; q < 4; ++q) {
          float a = acc[p][q];
          a = dot2u(av[p][0], bv[q][0], a);
          a = dot2u(av[p][1], bv[q][1], a);
          a = dot2u(av[p][2], bv[q][2], a);
          a = dot2u(av[p][3], bv[q][3], a);
          acc[p][q] = a;
        }
    }
    __syncthreads();
  }

  float* ob = out + (size_t)b * OO * HW;
  #pragma unroll
  for (int q = 0; q < 4; ++q) {
    f32x4 v;
    v[0] = acc[0][q]; v[1] = acc[1][q]; v[2] = acc[2][q]; v[3] = acc[3][q];
    *(f32x4*)(ob + (size_t)(og * 4 + q) * HW + hw0 + mg * 4) = v;
  }
}

extern "C" void kernel_launch(void* const* d_in, const int* in_sizes, int n_in,
                              void* d_out, int out_size, void* d_ws, size_t ws_size,
                              hipStream_t stream) {
  const float* x     = (const float*)d_in[0];
  const float* w_off = (const float*)d_in[1];
  const float* b_off = (const float*)d_in[2];
  const float* w_dcn = (const float*)d_in[3];
  float* out = (float*)d_out;

  char* ws = (char*)d_ws;
  float* offset = (float*)ws;                                      // 5,308,416 B
  unsigned short* xtp = (unsigned short*)(ws + 5308416);           // 9,437,184 B
  unsigned short* wtp = (unsigned short*)(ws + 5308416 + 9437184); //    73,728 B
  int* flag = (int*)(ws + 14819328);                               //         4 B

  transpose_kernel<<<NPIX / 64, 256, 0, stream>>>(x, xtp);
  wprep_kernel<<<(K2 * OO * CC) / 256, 256, 0, stream>>>(w_dcn, wtp);
  offconv_kernel<<<NPIX / 64, 256, 0, stream>>>(xtp, w_off, b_off, offset);
  dcn_mfma16<<<BB * NTILE, 256, 0, stream>>>(xtp, offset, wtp, out);
  check_kernel<<<1, 256, 0, stream>>>(x, offset, w_dcn, out, flag);
  dcn_fb<<<BB * NTILE, 256, 0, stream>>>(xtp, offset, wtp, out, flag);
}

// Round 10
// 95.112 us; speedup vs baseline: 1.2577x; 1.2577x over previous
//
#include <hip/hip_runtime.h>

#define BB 8
#define CC 64
#define HH 96
#define WW 96
#define OO 64
#define KK 3
#define K2 9
#define HW (HH*WW)      // 9216
#define NOFF 18
#define NPIX (BB*HW)    // 73728
#define MT 64           // pixels per dcn block
#define NTILE (HW/MT)   // 144 tiles per image
#define NXCD 8

typedef _Float16 f16;
typedef __attribute__((ext_vector_type(2))) _Float16 f16x2;
typedef __attribute__((ext_vector_type(4))) _Float16 f16x4;
typedef __attribute__((ext_vector_type(4))) float f32x4;
typedef __attribute__((ext_vector_type(4))) unsigned int uint4v;

// Legacy CDNA spelling — no __has_builtin guard (false on host pass, R8 lesson)
#define MFMA16(a,b,c) __builtin_amdgcn_mfma_f32_16x16x16f16(a,b,c,0,0,0)

#if __has_builtin(__builtin_amdgcn_fdot2)
__device__ __forceinline__ float dot2u(unsigned a, unsigned b, float c) {
  return __builtin_amdgcn_fdot2(__builtin_bit_cast(f16x2, a),
                                __builtin_bit_cast(f16x2, b), c, false);
}
#else
__device__ __forceinline__ float dot2u(unsigned a, unsigned b, float c) {
  f16x2 ha = __builtin_bit_cast(f16x2, a), hb = __builtin_bit_cast(f16x2, b);
  return c + (float)ha[0] * (float)hb[0] + (float)ha[1] * (float)hb[1];
}
#endif

__device__ __forceinline__ f16x2 bch(unsigned u) { return __builtin_bit_cast(f16x2, u); }
__device__ __forceinline__ unsigned bcu(f16x2 h) { return __builtin_bit_cast(unsigned, h); }

// LDS slot swizzle (row stride 128 B = 8 slots of 16 B) — verified R4/R5/R9
__device__ __forceinline__ int swz(int row, int g) {
  return g ^ (((row >> 2) ^ ((row & 3) << 1)) & 7);
}

// XCD-aware block remap: 1152 blocks = 8 XCDs x 144 -> image j on XCD j
__device__ __forceinline__ int xcd_remap(int bid) {
  return (bid & 7) * (NPIX / 64 / NXCD) + (bid >> 3);
}

// ---------------- Kernel T: NCHW fp32 -> NHWC f16 (verified R5 + swizzle) ---
__global__ __launch_bounds__(256) void transpose_kernel(
    const float* __restrict__ x, unsigned short* __restrict__ xt) {
  int t = threadIdx.x;
  int px = xcd_remap(blockIdx.x) * 64 + (t & 63);
  int cg = t >> 6;
  int b = px / HW, hw = px % HW;
  const float* xp = x + (size_t)b * CC * HW + (size_t)(cg * 16) * HW + hw;
  f16 r[16];
  #pragma unroll
  for (int i = 0; i < 16; ++i) r[i] = (f16)xp[i * HW];
  uint4v v0, v1;
  #pragma unroll
  for (int q = 0; q < 4; ++q) {
    f16x2 a = {r[q*2], r[q*2+1]};       v0[q] = bcu(a);
    f16x2 bq = {r[8+q*2], r[8+q*2+1]};  v1[q] = bcu(bq);
  }
  uint4v* dst = (uint4v*)(xt + (size_t)px * CC + cg * 16);
  dst[0] = v0; dst[1] = v1;
}

// ---------------- Kernel W: w_dcn [O][C][K2] fp32 -> wt [K2][O][C] f16 ------
__global__ void wprep_kernel(const float* __restrict__ w_dcn,
                             unsigned short* __restrict__ wt) {
  int idx = blockIdx.x * 256 + threadIdx.x;
  int k = idx / (OO * CC);
  int o = (idx / CC) % OO;
  int c = idx % CC;
  f16 h = (f16)w_dcn[(o * CC + c) * K2 + k];
  wt[idx] = __builtin_bit_cast(unsigned short, h);
}

// ---------------- Kernel O: offset conv via dot2 (verified R5 + swizzle) ----
#define JW 72
#define DOT4(xv, wv, a) do { a = dot2u((xv)[0],(wv)[0],a); a = dot2u((xv)[1],(wv)[1],a); \
                             a = dot2u((xv)[2],(wv)[2],a); a = dot2u((xv)[3],(wv)[3],a); } while(0)
#define DECLSET(R) uint4v R##0,R##1,R##2,R##3,R##4,R##5,R##6,R##7; bool vld##R = false;
#define LOADT(kt_, R) do { int ky=(kt_)/3, kx=(kt_)%3; int y=h-1+ky, xx=w-1+kx; \
  vld##R = ((unsigned)y<HH)&&((unsigned)xx<WW); \
  int yc=min(max(y,0),HH-1), xc=min(max(xx,0),WW-1); \
  const uint4v* xr_ = xtb + (size_t)(yc*WW+xc)*8; \
  R##0=xr_[0];R##1=xr_[1];R##2=xr_[2];R##3=xr_[3];R##4=xr_[4];R##5=xr_[5];R##6=xr_[6];R##7=xr_[7]; } while(0)
#define USET(kt_, R) do { if (vld##R) { \
  _Pragma("unroll") \
  for (int ji = 0; ji < 5; ++ji) { int j = jg + ji*4; \
    const uint4v* wr_ = (const uint4v*)&wl[((kt_)*NOFF + j)*JW]; \
    float a = acc[ji]; \
    DOT4(R##0,wr_[0],a); DOT4(R##1,wr_[1],a); DOT4(R##2,wr_[2],a); DOT4(R##3,wr_[3],a); \
    DOT4(R##4,wr_[4],a); DOT4(R##5,wr_[5],a); DOT4(R##6,wr_[6],a); DOT4(R##7,wr_[7],a); \
    if (j < NOFF) acc[ji] = a; } } } while(0)

__global__ __launch_bounds__(256) void offconv_kernel(
    const unsigned short* __restrict__ xt, const float* __restrict__ w_off,
    const float* __restrict__ b_off, float* __restrict__ offset) {
  __shared__ unsigned short wl[K2 * NOFF * JW + 2 * JW];
  int t = threadIdx.x;
  for (int i = t; i < K2 * NOFF * CC; i += 256) {
    int kt = i / (NOFF * CC);
    int r = i - kt * (NOFF * CC);
    int j = r >> 6, c = r & 63;
    f16 h = (f16)w_off[(j * CC + c) * K2 + kt];
    wl[(kt * NOFF + j) * JW + c] = __builtin_bit_cast(unsigned short, h);
  }
  __syncthreads();

  int px = xcd_remap(blockIdx.x) * 64 + (t >> 2);
  int jg = t & 3;
  int b = px / HW, hw = px % HW;
  int h = hw / WW, w = hw % WW;

  float acc[5];
  #pragma unroll
  for (int ji = 0; ji < 5; ++ji) {
    int j = jg + ji * 4;
    acc[ji] = (j < NOFF) ? b_off[j] : 0.f;
  }

  const uint4v* xtb = (const uint4v*)(xt + (size_t)b * HW * CC);
  DECLSET(A); DECLSET(B);
  LOADT(0, A);
  LOADT(1, B);
  #pragma unroll
  for (int kt = 0; kt < 7; kt += 2) {
    USET(kt, A);     LOADT(kt + 2, A);
    USET(kt + 1, B); if (kt + 3 < K2) LOADT(kt + 3, B);
  }
  USET(8, A);

  float* op = offset + (size_t)b * NOFF * HW + hw;
  #pragma unroll
  for (int ji = 0; ji < 5; ++ji) {
    int j = jg + ji * 4;
    if (j < NOFF) op[j * HW] = acc[ji];
  }
}

// ---------------- Kernel D: dcn via MFMA 16x16x16, 2-deep prefetch ----------
// Verified R9 formulas (staging, swizzle, fragment offsets, epilogue)
// + packed 16-B params, two static reg sets (A/B), XCD swizzle.
#define DECL_PSET(S) \
  uint4v c0a##S, c0b##S, c1a##S, c1b##S, c2a##S, c2b##S, c3a##S, c3b##S, \
         wv0##S, wv1##S; \
  unsigned w01##S, w23##S;

#define ISSUE_SET(S, k) do { \
  uint4v e = prm[(k) * 64 + sm]; \
  int i0 = (int)(e[0] & 0xffffu) << 7; \
  int i1 = (int)(e[0] >> 16) << 7; \
  int i2 = (int)(e[1] & 0xffffu) << 7; \
  int i3 = (int)(e[1] >> 16) << 7; \
  w01##S = e[2]; w23##S = e[3]; \
  c0a##S = *(const uint4v*)(xb + i0 + co); c0b##S = *(const uint4v*)(xb + i0 + co + 16); \
  c1a##S = *(const uint4v*)(xb + i1 + co); c1b##S = *(const uint4v*)(xb + i1 + co + 16); \
  c2a##S = *(const uint4v*)(xb + i2 + co); c2b##S = *(const uint4v*)(xb + i2 + co + 16); \
  c3a##S = *(const uint4v*)(xb + i3 + co); c3b##S = *(const uint4v*)(xb + i3 + co + 16); \
  const uint4v* wk = (const uint4v*)((const char*)wt \
                      + ((size_t)(k) * OO + sm) * (CC * 2) + cb * 32); \
  wv0##S = wk[0]; wv1##S = wk[1]; \
} while(0)

#define STAGE_SET(S) do { \
  *(uint4v*)&Bl[sm * 128 + (((cb * 2 + 0) ^ fs) << 4)] = wv0##S; \
  *(uint4v*)&Bl[sm * 128 + (((cb * 2 + 1) ^ fs) << 4)] = wv1##S; \
  f16x2 wA = bch(w01##S), wB = bch(w23##S); \
  f16x2 p0 = {wA[0], wA[0]}, p1 = {wA[1], wA[1]}; \
  f16x2 p2 = {wB[0], wB[0]}, p3 = {wB[1], wB[1]}; \
  uint4v pa, pb2; \
  _Pragma("unroll") \
  for (int q = 0; q < 4; ++q) { \
    f16x2 s  = p0 * bch(c0a##S[q]) + p1 * bch(c1a##S[q]) \
             + p2 * bch(c2a##S[q]) + p3 * bch(c3a##S[q]); \
    pa[q] = bcu(s); \
    f16x2 s2 = p0 * bch(c0b##S[q]) + p1 * bch(c1b##S[q]) \
             + p2 * bch(c2b##S[q]) + p3 * bch(c3b##S[q]); \
    pb2[q] = bcu(s2); \
  } \
  *(uint4v*)&Al[sm * 128 + (((cb * 2 + 0) ^ fs) << 4)] = pa; \
  *(uint4v*)&Al[sm * 128 + (((cb * 2 + 1) ^ fs) << 4)] = pb2; \
} while(0)

#define MFMA_PHASE do { \
  _Pragma("unroll") \
  for (int q = 0; q < 4; ++q) { \
    f16x4 aq = *(const f16x4*)&Al[aoff[q]]; \
    _Pragma("unroll") \
    for (int nb = 0; nb < 4; ++nb) { \
      f16x4 bq = *(const f16x4*)&Bl[boff[nb][q]]; \
      acc[nb] = MFMA16(aq, bq, acc[nb]); \
    } \
  } \
} while(0)

#define TAP(S, kn) do { \
  STAGE_SET(S); \
  __syncthreads(); \
  ISSUE_SET(S, kn); \
  MFMA_PHASE; \
  __syncthreads(); \
} while(0)

#define TAP_LAST(S) do { \
  STAGE_SET(S); \
  __syncthreads(); \
  MFMA_PHASE; \
  __syncthreads(); \
} while(0)

__global__ __launch_bounds__(256) void dcn_mfma16(
    const unsigned short* __restrict__ xt,   // [B][HW][C] f16
    const float* __restrict__ offset,        // [B][18][HW] fp32
    const unsigned short* __restrict__ wt,   // [K2][O][C] f16
    float* __restrict__ out) {
  __shared__ uint4v prm[576];   // {i01, i23, w01(f16x2), w23(f16x2)} per (k,m)
  __shared__ char Al[64 * 128];
  __shared__ char Bl[64 * 128];

  int t = threadIdx.x;
  int blk = xcd_remap(blockIdx.x);
  int b = blk / NTILE;
  int hw0 = (blk % NTILE) * MT;

  const char*  xb   = (const char*)(xt + (size_t)b * HW * CC);
  const float* offb = offset + (size_t)b * NOFF * HW + hw0;

  // ---- phase 0: bilinear params, packed 16 B/entry (math verified R3..R9) --
  for (int p = t; p < 576; p += 256) {
    int k = p >> 6, m = p & 63;
    int hw = hw0 + m;
    int h = hw / WW, w = hw % WW;
    int ky = k / KK, kx = k % KK;
    float py = offb[(2 * k) * HW + m]     + (float)(h - 1 + ky);
    float px = offb[(2 * k + 1) * HW + m] + (float)(w - 1 + kx);
    float y0f = floorf(py), x0f = floorf(px);
    float wy = py - y0f, wx = px - x0f;
    int y0 = (int)y0f, x0 = (int)x0f;
    int y1 = y0 + 1, x1 = x0 + 1;
    bool vy0 = (unsigned)y0 < HH, vy1 = (unsigned)y1 < HH;
    bool vx0 = (unsigned)x0 < WW, vx1 = (unsigned)x1 < WW;
    int cy0 = min(max(y0, 0), HH - 1), cy1 = min(max(y1, 0), HH - 1);
    int cx0 = min(max(x0, 0), WW - 1), cx1 = min(max(x1, 0), WW - 1);
    float g00 = (1.f - wy) * (1.f - wx) * ((vy0 && vx0) ? 1.f : 0.f);
    float g01 = (1.f - wy) * wx         * ((vy0 && vx1) ? 1.f : 0.f);
    float g10 = wy * (1.f - wx)         * ((vy1 && vx0) ? 1.f : 0.f);
    float g11 = wy * wx                 * ((vy1 && vx1) ? 1.f : 0.f);
    unsigned i01 = (unsigned)(cy0 * WW + cx0) | ((unsigned)(cy0 * WW + cx1) << 16);
    unsigned i23 = (unsigned)(cy1 * WW + cx0) | ((unsigned)(cy1 * WW + cx1) << 16);
    f16x2 wa = {(f16)g00, (f16)g01};
    f16x2 wb = {(f16)g10, (f16)g11};
    prm[p] = (uint4v){i01, i23, bcu(wa), bcu(wb)};
  }
  __syncthreads();

  // staging mapping (verified R5/R9)
  int sm = (t & 15) + (t >> 6) * 16;
  int cb = (t >> 4) & 3;
  int fs = ((sm >> 2) ^ ((sm & 3) << 1)) & 7;
  int co = cb * 32;

  // wave geometry + tap-invariant fragment offsets (verified R9)
  int wv = t >> 6;
  int l  = t & 63;
  int lr = l & 15, lh = l >> 4;
  int Ra = wv * 16 + lr;
  int aoff[4];
  int boff[4][4];
  #pragma unroll
  for (int q = 0; q < 4; ++q) {
    aoff[q] = Ra * 128 + (swz(Ra, 2 * q + (lh >> 1)) << 4) + ((lh & 1) << 3);
    #pragma unroll
    for (int nb = 0; nb < 4; ++nb) {
      int Rb = nb * 16 + lr;
      boff[nb][q] = Rb * 128 + (swz(Rb, 2 * q + (lh >> 1)) << 4) + ((lh & 1) << 3);
    }
  }

  f32x4 acc[4];
  #pragma unroll
  for (int nb = 0; nb < 4; ++nb) acc[nb] = (f32x4){0.f, 0.f, 0.f, 0.f};

  DECL_PSET(A)
  DECL_PSET(B)

  // 2-deep prefetch, static A/B alternation over 9 taps
  ISSUE_SET(A, 0);
  ISSUE_SET(B, 1);
  TAP(A, 2);      // tap 0
  TAP(B, 3);      // tap 1
  TAP(A, 4);      // tap 2
  TAP(B, 5);      // tap 3
  TAP(A, 6);      // tap 4
  TAP(B, 7);      // tap 5
  TAP(A, 8);      // tap 6
  TAP_LAST(B);    // tap 7
  TAP_LAST(A);    // tap 8

  // ---- epilogue (verified R9) ----
  float* ob = out + (size_t)b * OO * HW;
  #pragma unroll
  for (int nb = 0; nb < 4; ++nb) {
    int o = nb * 16 + lr;
    int m = wv * 16 + lh * 4;
    *(f32x4*)(ob + (size_t)o * HW + hw0 + m) = acc[nb];
  }
}

extern "C" void kernel_launch(void* const* d_in, const int* in_sizes, int n_in,
                              void* d_out, int out_size, void* d_ws, size_t ws_size,
                              hipStream_t stream) {
  const float* x     = (const float*)d_in[0];
  const float* w_off = (const float*)d_in[1];
  const float* b_off = (const float*)d_in[2];
  const float* w_dcn = (const float*)d_in[3];
  float* out = (float*)d_out;

  char* ws = (char*)d_ws;
  float* offset = (float*)ws;                                      // 5,308,416 B
  unsigned short* xtp = (unsigned short*)(ws + 5308416);           // 9,437,184 B
  unsigned short* wtp = (unsigned short*)(ws + 5308416 + 9437184); //    73,728 B

  transpose_kernel<<<NPIX / 64, 256, 0, stream>>>(x, xtp);
  wprep_kernel<<<(K2 * OO * CC) / 256, 256, 0, stream>>>(w_dcn, wtp);
  offconv_kernel<<<NPIX / 64, 256, 0, stream>>>(xtp, w_off, b_off, offset);
  dcn_mfma16<<<NPIX / 64, 256, 0, stream>>>(xtp, offset, wtp, out);
}